// Round 3
// baseline (218.241 us; speedup 1.0000x reference)
//
#include <hip/hip_runtime.h>

// Problem dims (fixed by reference): B=8, L=12, T=1024, H=256
#define RWS 96      // B*L rows
#define TT  1024    // timesteps
#define HH  256     // features
#define CT  64      // timesteps per chunk/block
#define NC  (TT/CT) // 16 chunks per row
#define MAGIC 0x5EEDF00Du

// Single-pass fused kernel with decoupled lookback.
// Block = (row, chunk of 64 t). Wave w owns 16 contiguous timesteps; lane owns
// 4 contiguous features. The 64KB h-chunk lives entirely in registers
// (16 float4/thread), so h is read from HBM exactly ONCE.
__global__ __launch_bounds__(256) void fused_scan(
    const float* __restrict__ h, const float* __restrict__ attn_w,
    const float* __restrict__ attn_b, float* __restrict__ Wrec,
    float* __restrict__ esum_g, unsigned int* __restrict__ flags,
    float* __restrict__ out) {
  const int blk  = blockIdx.x;
  const int row  = blk / NC;
  const int c    = blk % NC;
  const int tid  = threadIdx.x;
  const int lane = tid & 63;
  const int wave = tid >> 6;
  const int t0   = c * CT + wave * 16;  // this wave's 16 timesteps

  const float4 wv  = reinterpret_cast<const float4*>(attn_w)[lane];
  const float bias = attn_b[0];

  const float4* hp =
      reinterpret_cast<const float4*>(h + ((size_t)row * TT + t0) * HH) + lane;

  // ---- phase 1: load chunk into registers, compute e[t], subgroup W sums ----
  float4 hv[16];
  float ew[16];
#pragma unroll
  for (int i = 0; i < 16; ++i) hv[i] = hp[(size_t)i * (HH / 4)];

  float4 wacc = make_float4(0.f, 0.f, 0.f, 0.f);
  float esub = 0.f;
#pragma unroll
  for (int i = 0; i < 16; ++i) {
    float p = hv[i].x * wv.x + hv[i].y * wv.y + hv[i].z * wv.z + hv[i].w * wv.w;
#pragma unroll
    for (int off = 32; off; off >>= 1) p += __shfl_xor(p, off);
    const float e = __expf(p + bias);
    ew[i] = e;
    esub += e;
    wacc.x = fmaf(e, hv[i].x, wacc.x);
    wacc.y = fmaf(e, hv[i].y, wacc.y);
    wacc.z = fmaf(e, hv[i].z, wacc.z);
    wacc.w = fmaf(e, hv[i].w, wacc.w);
  }

  __shared__ float4 wlds[4][64];  // [wave][lane] subgroup W sums
  __shared__ float  elds[4];      // subgroup e sums
  __shared__ float  gWf[HH];      // global W prefix (lookback result)
  __shared__ float  gE[1];        // global e prefix
  wlds[wave][lane] = wacc;
  if (lane == 0) elds[wave] = esub;
  __syncthreads();  // (1) wlds/elds ready

  // ---- publish chunk aggregate (skip last chunk: no consumers) ----
  if (c < NC - 1) {
    const float* wf = (const float*)wlds;
    const float tot =
        wf[0 * HH + tid] + wf[1 * HH + tid] + wf[2 * HH + tid] + wf[3 * HH + tid];
    __hip_atomic_store(&Wrec[(size_t)blk * HH + tid], tot, __ATOMIC_RELAXED,
                       __HIP_MEMORY_SCOPE_AGENT);
    if (tid == 0) {
      const float et = elds[0] + elds[1] + elds[2] + elds[3];
      __hip_atomic_store(&esum_g[blk], et, __ATOMIC_RELAXED,
                         __HIP_MEMORY_SCOPE_AGENT);
    }
    __syncthreads();  // (2) all record stores issued+drained
    if (tid == 0) {
      __threadfence();
      __hip_atomic_store(&flags[blk], MAGIC, __ATOMIC_RELEASE,
                         __HIP_MEMORY_SCOPE_AGENT);
    }
  }

  // ---- lookback: sum predecessor chunk aggregates ----
  float4 run = make_float4(0.f, 0.f, 0.f, 0.f);
  float cum = 0.f;
  if (c > 0) {
    if (tid == 0) {
      for (int cc = row * NC; cc < blk; ++cc)
        while (__hip_atomic_load(&flags[cc], __ATOMIC_ACQUIRE,
                                 __HIP_MEMORY_SCOPE_AGENT) != MAGIC)
          __builtin_amdgcn_s_sleep(2);
    }
    __syncthreads();  // (3) all predecessors published
    float s = 0.f;
    for (int cc = row * NC; cc < blk; ++cc)
      s += __hip_atomic_load(&Wrec[(size_t)cc * HH + tid], __ATOMIC_RELAXED,
                             __HIP_MEMORY_SCOPE_AGENT);
    gWf[tid] = s;
    if (tid == 0) {
      float ep = 0.f;
      for (int cc = row * NC; cc < blk; ++cc)
        ep += __hip_atomic_load(&esum_g[cc], __ATOMIC_RELAXED,
                                __HIP_MEMORY_SCOPE_AGENT);
      gE[0] = ep;
    }
    __syncthreads();  // (4) gWf/gE ready
    run.x = gWf[4 * lane + 0];
    run.y = gWf[4 * lane + 1];
    run.z = gWf[4 * lane + 2];
    run.w = gWf[4 * lane + 3];
    cum = gE[0];
  }

  // intra-chunk prefix: subgroups before this wave
  for (int w2 = 0; w2 < wave; ++w2) {
    const float4 wp = wlds[w2][lane];
    run.x += wp.x; run.y += wp.y; run.z += wp.z; run.w += wp.w;
    cum += elds[w2];
  }

  // ---- phase 2: sequential scan over this wave's 16 timesteps ----
  float4* op =
      reinterpret_cast<float4*>(out + ((size_t)row * TT + t0) * HH) + lane;
#pragma unroll
  for (int i = 0; i < 16; ++i) {
    const float e = ew[i];
    cum += e;
    const float ic = __builtin_amdgcn_rcpf(cum + 1e-12f);
    run.x = fmaf(e, hv[i].x, run.x);
    run.y = fmaf(e, hv[i].y, run.y);
    run.z = fmaf(e, hv[i].z, run.z);
    run.w = fmaf(e, hv[i].w, run.w);
    float4 o;
    o.x = fmaf(run.x, ic, hv[i].x);
    o.y = fmaf(run.y, ic, hv[i].y);
    o.z = fmaf(run.z, ic, hv[i].z);
    o.w = fmaf(run.w, ic, hv[i].w);
    op[(size_t)i * (HH / 4)] = o;
  }
}

extern "C" void kernel_launch(void* const* d_in, const int* in_sizes, int n_in,
                              void* d_out, int out_size, void* d_ws,
                              size_t ws_size, hipStream_t stream) {
  const float* h      = (const float*)d_in[0];
  const float* attn_w = (const float*)d_in[1];
  const float* attn_b = (const float*)d_in[2];
  float* out = (float*)d_out;

  // workspace: Wrec[RWS*NC*HH] floats, esum[RWS*NC], flags[RWS*NC] (~1.6 MB)
  float* Wrec   = (float*)d_ws;
  float* esum_g = Wrec + (size_t)RWS * NC * HH;
  unsigned int* flags = (unsigned int*)(esum_g + RWS * NC);

  fused_scan<<<RWS * NC, 256, 0, stream>>>(h, attn_w, attn_b, Wrec, esum_g,
                                           flags, out);
}

// Round 5
// 56.709 us; speedup vs baseline: 3.8485x; 3.8485x over previous
//
#include <hip/hip_runtime.h>

// Problem dims (fixed by reference): B=8, L=12, T=1024, H=256
#define RWS 96      // B*L rows
#define TT  1024    // timesteps
#define HH  256     // features
#define CT  64      // timesteps per chunk
#define NC  (TT/CT) // 16 chunks per row

typedef float f32x4 __attribute__((ext_vector_type(4)));

// ---------------------------------------------------------------------------
// Pass 1: per chunk (row,c): e[t]=exp(h[t]·w + b) and chunk partial weighted
// sums W[row][c][f] = sum_{t in chunk} e[t]*h[t][f]. Reads h exactly once.
// 256 threads: wave-per-timestep dot (float4/lane + shfl reduce); per-lane
// weighted acc combined across the 4 waves via LDS. Grid 1536 = 6 blocks/CU.
// ---------------------------------------------------------------------------
__global__ __launch_bounds__(256) void ta_pass1(
    const float* __restrict__ h, const float* __restrict__ attn_w,
    const float* __restrict__ attn_b, float* __restrict__ e_g,
    float* __restrict__ W_g) {
  const int blk  = blockIdx.x;
  const int row  = blk / NC;
  const int c    = blk % NC;
  const int t0   = c * CT;
  const int tid  = threadIdx.x;
  const int lane = tid & 63;
  const int wave = tid >> 6;

  const float4 wv  = reinterpret_cast<const float4*>(attn_w)[lane];
  const float bias = attn_b[0];
  const float* hrow = h + (size_t)row * TT * HH;

  float4 acc = make_float4(0.f, 0.f, 0.f, 0.f);

  for (int tt = wave; tt < CT; tt += 4) {
    const int t = t0 + tt;
    const float4 hv =
        reinterpret_cast<const float4*>(hrow + (size_t)t * HH)[lane];
    float p = hv.x * wv.x + hv.y * wv.y + hv.z * wv.z + hv.w * wv.w;
#pragma unroll
    for (int off = 32; off; off >>= 1) p += __shfl_xor(p, off);
    const float e = __expf(p + bias);
    if (lane == 0) e_g[(size_t)row * TT + t] = e;
    acc.x = fmaf(e, hv.x, acc.x);
    acc.y = fmaf(e, hv.y, acc.y);
    acc.z = fmaf(e, hv.z, acc.z);
    acc.w = fmaf(e, hv.w, acc.w);
  }

  __shared__ float wlds[4][HH];
  reinterpret_cast<float4*>(wlds[wave])[lane] = acc;
  __syncthreads();
  const float wsum = wlds[0][tid] + wlds[1][tid] + wlds[2][tid] + wlds[3][tid];
  W_g[((size_t)row * NC + c) * HH + tid] = wsum;
}

// ---------------------------------------------------------------------------
// Pass 2: ONE WAVE per 64-t chunk (grid 1536 = exactly 6 blocks/CU — the R1
// version's 384-block grid left half the CUs idle for half the kernel).
// Lane owns 4 contiguous features. Chunk e values sit one-per-lane and are
// broadcast via __shfl (readlane). Prefixes (e over [0,ts), W over chunks <c)
// are <=15 coalesced L2-hit iterations. h loads and out stores nontemporal so
// the 192 MB of streaming traffic doesn't evict the hot e/W records.
// ---------------------------------------------------------------------------
__global__ __launch_bounds__(64) void ta_pass2(
    const float* __restrict__ h, const float* __restrict__ e_g,
    const float* __restrict__ W_g, float* __restrict__ out) {
  const int blk  = blockIdx.x;
  const int row  = blk >> 4;   // / NC
  const int c    = blk & (NC - 1);
  const int ts   = c * CT;
  const int lane = threadIdx.x;

  const float* er = e_g + (size_t)row * TT;
  const float ev = er[ts + lane];  // this chunk's e values, one per lane

  // exclusive e-prefix: sum e[0:ts)
  float ex = 0.f;
  for (int i = lane; i < ts; i += 64) ex += er[i];
#pragma unroll
  for (int off = 32; off; off >>= 1) ex += __shfl_xor(ex, off);

  // exclusive W-prefix over chunks < c (lane's 4 features)
  float4 run = make_float4(0.f, 0.f, 0.f, 0.f);
  const float4* Wp =
      reinterpret_cast<const float4*>(W_g + (size_t)row * NC * HH) + lane;
  for (int cc = 0; cc < c; ++cc) {
    const float4 wv = Wp[(size_t)cc * (HH / 4)];
    run.x += wv.x; run.y += wv.y; run.z += wv.z; run.w += wv.w;
  }

  const f32x4* hp =
      reinterpret_cast<const f32x4*>(h + ((size_t)row * TT + ts) * HH) + lane;
  f32x4* op =
      reinterpret_cast<f32x4*>(out + ((size_t)row * TT + ts) * HH) + lane;

  float cum = ex;
#pragma unroll 8
  for (int tt = 0; tt < CT; ++tt) {
    const float e = __shfl(ev, tt);  // uniform idx -> readlane broadcast
    cum += e;
    const float ic = __builtin_amdgcn_rcpf(cum + 1e-12f);
    const f32x4 hv = __builtin_nontemporal_load(hp + (size_t)tt * (HH / 4));
    run.x = fmaf(e, hv.x, run.x);
    run.y = fmaf(e, hv.y, run.y);
    run.z = fmaf(e, hv.z, run.z);
    run.w = fmaf(e, hv.w, run.w);
    f32x4 o;
    o.x = fmaf(run.x, ic, hv.x);
    o.y = fmaf(run.y, ic, hv.y);
    o.z = fmaf(run.z, ic, hv.z);
    o.w = fmaf(run.w, ic, hv.w);
    __builtin_nontemporal_store(o, op + (size_t)tt * (HH / 4));
  }
}

extern "C" void kernel_launch(void* const* d_in, const int* in_sizes, int n_in,
                              void* d_out, int out_size, void* d_ws,
                              size_t ws_size, hipStream_t stream) {
  const float* h      = (const float*)d_in[0];
  const float* attn_w = (const float*)d_in[1];
  const float* attn_b = (const float*)d_in[2];
  float* out = (float*)d_out;

  // workspace layout (floats): e[R*T], W[R*NC*H]  (~1.9 MB)
  float* e_g = (float*)d_ws;
  float* W_g = e_g + (size_t)RWS * TT;

  ta_pass1<<<RWS * NC, 256, 0, stream>>>(h, attn_w, attn_b, e_g, W_g);
  ta_pass2<<<RWS * NC, 64, 0, stream>>>(h, e_g, W_g, out);
}